// Round 5
// baseline (571.884 us; speedup 1.0000x reference)
//
#include <hip/hip_runtime.h>

#define N_NODES 100000
#define N_EDGES 3200000
#define BATCH 16
#define BKT_SHIFT 6
#define BKT_NODES 64
#define K_BUCKETS 1563                 // ceil(100000/64)
#define NB 512                         // subchunks (E/NB = 6250 exact)
#define SUB (N_EDGES / NB)             // 6250
#define FT 512                         // fill threads per block
#define SCAN_T 256
#define SCAN_C 7                       // 256*7 = 1792 >= 1563
#define CAP 4096                       // nodesort LDS capacity (bucket avg 2047, sigma 45)

typedef float v4f __attribute__((ext_vector_type(4)));

// ---- phase 1: per-subchunk LDS histogram of row-buckets ----
__global__ void hist_kernel(const int* __restrict__ row, int* __restrict__ blk_cnt) {
    __shared__ int lh[K_BUCKETS];
    int t = threadIdx.x, blk = blockIdx.x;
    for (int k = t; k < K_BUCKETS; k += 256) lh[k] = 0;
    __syncthreads();
    int base = blk * SUB;
    for (int e = base + t; e < base + SUB; e += 256)
        atomicAdd(&lh[row[e] >> BKT_SHIFT], 1);
    __syncthreads();
    for (int k = t; k < K_BUCKETS; k += 256)
        blk_cnt[k * NB + blk] = lh[k];
}

// ---- phase 2: per-bucket exclusive prefix over the NB subchunks; totals.
// One WAVE per bucket: 64 lanes x 8 elements, wave-scan via shfl_up.
__global__ void colscan_kernel(int* __restrict__ blk_cnt, int* __restrict__ totals) {
    int wid = (blockIdx.x * blockDim.x + threadIdx.x) >> 6;
    int lane = threadIdx.x & 63;
    if (wid >= K_BUCKETS) return;
    int* p = &blk_cnt[wid * NB + lane * 8];
    int4 a = ((int4*)p)[0];
    int4 b = ((int4*)p)[1];
    int lt = a.x + a.y + a.z + a.w + b.x + b.y + b.z + b.w;
    // wave-inclusive scan of per-lane totals
    int pref = lt;
    #pragma unroll
    for (int off = 1; off < 64; off <<= 1) {
        int v = __shfl_up(pref, off, 64);
        if (lane >= off) pref += v;
    }
    int run = pref - lt;                 // exclusive base for this lane
    int4 oa, ob;
    oa.x = run; run += a.x;
    oa.y = run; run += a.y;
    oa.z = run; run += a.z;
    oa.w = run; run += a.w;
    ob.x = run; run += b.x;
    ob.y = run; run += b.y;
    ob.z = run; run += b.z;
    ob.w = run; run += b.w;
    ((int4*)p)[0] = oa;
    ((int4*)p)[1] = ob;
    int tot = __shfl(pref, 63, 64);      // inclusive total of bucket
    if (lane == 0) totals[wid] = tot;
}

// ---- phase 3: exclusive scan of 1563 bucket totals -> bptr ----
__global__ void scan_kernel(const int* __restrict__ totals, int* __restrict__ bptr,
                            int* __restrict__ row_ptr) {
    __shared__ int s[SCAN_T];
    int t = threadIdx.x;
    int loc[SCAN_C];
    int sum = 0;
    for (int i = 0; i < SCAN_C; i++) {
        int idx = t * SCAN_C + i;
        int v = (idx < K_BUCKETS) ? totals[idx] : 0;
        loc[i] = v;
        sum += v;
    }
    s[t] = sum;
    __syncthreads();
    for (int off = 1; off < SCAN_T; off <<= 1) {   // Hillis-Steele inclusive
        int x = (t >= off) ? s[t - off] : 0;
        __syncthreads();
        s[t] += x;
        __syncthreads();
    }
    int excl = s[t] - sum;
    for (int i = 0; i < SCAN_C; i++) {
        int idx = t * SCAN_C + i;
        if (idx < K_BUCKETS) bptr[idx] = excl;
        excl += loc[i];
    }
    if (t == 0) { bptr[K_BUCKETS] = N_EDGES; row_ptr[N_NODES] = N_EDGES; }
}

// ---- phase 4: LDS counting sort per 6250-edge subchunk, then run copy-out.
// 63.0 KB LDS -> 2 blocks/CU. record: x = (r_local<<17)|col, y = w bits.
__global__ void __launch_bounds__(FT) fill_kernel(
        const int* __restrict__ row, const int* __restrict__ col,
        const float* __restrict__ w,
        const int* __restrict__ bptr, const int* __restrict__ blk_cnt,
        uint2* __restrict__ entries) {
    __shared__ uint2 sbuf[SUB];          // 50000 B
    __shared__ int lbeg[K_BUCKETS];      // 6252 B
    __shared__ int lcur[K_BUCKETS];      // 6252 B
    __shared__ int sscan[FT];            // 2048 B   (total 63.0 KB)
    int t = threadIdx.x, blk = blockIdx.x;
    for (int k = t; k < K_BUCKETS; k += FT) lcur[k] = 0;
    __syncthreads();
    int base = blk * SUB;
    // pass 1: histogram into lcur
    for (int e = base + t; e < base + SUB; e += FT)
        atomicAdd(&lcur[row[e] >> BKT_SHIFT], 1);
    __syncthreads();
    // block-wide exclusive scan (each thread owns 4 buckets)
    int loc[4];
    int sum = 0;
    #pragma unroll
    for (int j = 0; j < 4; j++) {
        int k = t * 4 + j;
        int v = (k < K_BUCKETS) ? lcur[k] : 0;
        loc[j] = v;
        sum += v;
    }
    sscan[t] = sum;
    __syncthreads();
    for (int off = 1; off < FT; off <<= 1) {
        int x = (t >= off) ? sscan[t - off] : 0;
        __syncthreads();
        sscan[t] += x;
        __syncthreads();
    }
    int excl = sscan[t] - sum;
    #pragma unroll
    for (int j = 0; j < 4; j++) {
        int k = t * 4 + j;
        if (k < K_BUCKETS) { lbeg[k] = excl; lcur[k] = excl; }
        excl += loc[j];
    }
    __syncthreads();
    // pass 2: place records into LDS (bucket-sorted)
    for (int e = base + t; e < base + SUB; e += FT) {
        int r = row[e];
        int bkt = r >> BKT_SHIFT;
        int pos = atomicAdd(&lcur[bkt], 1);
        sbuf[pos] = make_uint2(((unsigned)(r & (BKT_NODES - 1)) << 17) | (unsigned)col[e],
                               __float_as_uint(w[e]));
    }
    __syncthreads();
    // pass 3: 4-lane subgroups copy each bucket run out (avg run ~4)
    int lane = t & 3;
    for (int k = (t >> 2); k < K_BUCKETS; k += FT / 4) {
        int lb = lbeg[k];
        int le = lcur[k];
        int dst = bptr[k] + blk_cnt[k * NB + blk];
        for (int i = lb + lane; i < le; i += 4)
            entries[dst + (i - lb)] = sbuf[i];
    }
}

// ---- phase 5: in-place per-bucket sort by node (LDS-staged); emits row_ptr ----
__global__ void nodesort_kernel(const int* __restrict__ bptr, uint2* __restrict__ entries,
                                int* __restrict__ row_ptr) {
    __shared__ uint2 ebuf[CAP];          // 32 KB
    __shared__ int nh[BKT_NODES];
    __shared__ int nc[BKT_NODES];
    int t = threadIdx.x, b = blockIdx.x;
    int beg = bptr[b], end = bptr[b + 1];
    int n = min(end - beg, CAP);
    if (t < BKT_NODES) nh[t] = 0;
    __syncthreads();
    for (int k = t; k < n; k += 256) {
        uint2 r = entries[beg + k];
        ebuf[k] = r;
        atomicAdd(&nh[r.x >> 17], 1);
    }
    __syncthreads();
    if (t == 0) {
        int acc = 0;
        for (int i = 0; i < BKT_NODES; i++) {
            int v = nh[i];
            int node = b * BKT_NODES + i;
            if (node < N_NODES) row_ptr[node] = beg + acc;
            nc[i] = acc;
            acc += v;
        }
    }
    __syncthreads();
    for (int k = t; k < n; k += 256) {
        uint2 r = ebuf[k];
        int pos = atomicAdd(&nc[r.x >> 17], 1);
        entries[beg + pos] = r;
    }
}

// ---- x -> SoA plane layout: plane h holds cols [8h, 8h+8) of each node ----
__global__ void split_kernel(const float* __restrict__ x, float* __restrict__ planes) {
    int node = blockIdx.x * blockDim.x + threadIdx.x;
    if (node >= N_NODES) return;
    const float4* src = (const float4*)&x[node * BATCH];
    float4 a0 = src[0], a1 = src[1], a2 = src[2], a3 = src[3];
    float4* p0 = (float4*)&planes[(size_t)node * 8];
    p0[0] = a0; p0[1] = a1;
    float4* p1 = (float4*)&planes[(size_t)N_NODES * 8 + (size_t)node * 8];
    p1[0] = a2; p1[1] = a3;
}

// ---- non-temporal helpers: streams (entries, row_ptr, out) bypass L2/LLC so
// the 3.2-MB y plane is the ONLY allocator in each XCD's 4-MB L2.
__device__ __forceinline__ uint2 nt_load_e(const uint2* p) {
    unsigned long long v = __builtin_nontemporal_load((const unsigned long long*)p);
    return make_uint2((unsigned)v, (unsigned)(v >> 32));
}

// ---- layer pass: CSR pull over ONE 8-col plane. 2 threads/node, float4 quad
// each, 8-deep pipeline. Plane loads cached (L2-resident); everything else NT.
// Accumulation order per (node,col) identical to the monolithic version.
__global__ void __launch_bounds__(256) pull_half_kernel(
        const float* __restrict__ yplanes,    // plane h at + h*N*8
        const uint2* __restrict__ entries,
        const int* __restrict__ row_ptr,
        float* __restrict__ out,
        int half, int out_interleaved) {
    int tid = blockIdx.x * blockDim.x + threadIdx.x;
    int node = tid >> 1;
    int q = tid & 1;
    if (node >= N_NODES) return;
    const float* in = yplanes + (size_t)half * N_NODES * 8 + q * 4;
    int beg = __builtin_nontemporal_load(&row_ptr[node]);
    int end = __builtin_nontemporal_load(&row_ptr[node + 1]);
    float4 acc = make_float4(0.f, 0.f, 0.f, 0.f);
    if (beg < end) {
        int lim = end - 1;
        uint2 r[8];
        #pragma unroll
        for (int j = 0; j < 8; j++) r[j] = nt_load_e(&entries[min(beg + j, lim)]);
        int i = beg;
        while (i + 8 <= end) {
            float4 yv[8];
            #pragma unroll
            for (int j = 0; j < 8; j++)
                yv[j] = *(const float4*)&in[(r[j].x & 0x1FFFFu) * 8];
            uint2 nx[8];
            #pragma unroll
            for (int j = 0; j < 8; j++)
                nx[j] = nt_load_e(&entries[min(i + 8 + j, lim)]);
            #pragma unroll
            for (int j = 0; j < 8; j++) {
                float wj = __uint_as_float(r[j].y);
                acc.x += wj * yv[j].x;
                acc.y += wj * yv[j].y;
                acc.z += wj * yv[j].z;
                acc.w += wj * yv[j].w;
            }
            #pragma unroll
            for (int j = 0; j < 8; j++) r[j] = nx[j];
            i += 8;
        }
        if (i < end) {                       // masked epilogue, still batched
            float4 yv[8];
            #pragma unroll
            for (int j = 0; j < 8; j++)
                yv[j] = *(const float4*)&in[(r[j].x & 0x1FFFFu) * 8];
            #pragma unroll
            for (int j = 0; j < 8; j++)
                if (i + j < end) {
                    float wj = __uint_as_float(r[j].y);
                    acc.x += wj * yv[j].x;
                    acc.y += wj * yv[j].y;
                    acc.z += wj * yv[j].z;
                    acc.w += wj * yv[j].w;
                }
        }
    }
    size_t dst = out_interleaved
        ? (size_t)node * BATCH + half * 8 + q * 4
        : (size_t)half * N_NODES * 8 + (size_t)node * 8 + q * 4;
    v4f av = {acc.x, acc.y, acc.z, acc.w};
    __builtin_nontemporal_store(av, (v4f*)&out[dst]);
}

extern "C" void kernel_launch(void* const* d_in, const int* in_sizes, int n_in,
                              void* d_out, int out_size, void* d_ws, size_t ws_size,
                              hipStream_t stream) {
    const float* x   = (const float*)d_in[0];
    const float* w   = (const float*)d_in[1];
    const int*   row = (const int*)d_in[2];
    const int*   col = (const int*)d_in[3];
    float*       out = (float*)d_out;

    // ---- workspace carve-up (~32.4 MB; proven ws >= 33.2 MB) ----
    char* p = (char*)d_ws;
    uint2* entries = (uint2*)p;  p += (size_t)N_EDGES * sizeof(uint2);           // 25.6 MB
    float* buf     = (float*)p;                                                   // 6.4 MB (plane ping-pong)
    int*   blk_cnt = (int*)buf;  // 3.2 MB alias: dead before first pull writes buf
    p += (size_t)N_NODES * BATCH * sizeof(float);
    int* totals  = (int*)p;      p += 8192;
    int* bptr    = (int*)p;      p += 8192;
    int* row_ptr = (int*)p;      // 400 KB

    // ---- build exact per-node CSR (once; reused by all 4 layers) ----
    hist_kernel<<<NB, 256, 0, stream>>>(row, blk_cnt);
    colscan_kernel<<<(K_BUCKETS * 64 + 255) / 256, 256, 0, stream>>>(blk_cnt, totals);
    scan_kernel<<<1, SCAN_T, 0, stream>>>(totals, bptr, row_ptr);
    fill_kernel<<<NB, FT, 0, stream>>>(row, col, w, bptr, blk_cnt, entries);
    nodesort_kernel<<<K_BUCKETS, 256, 0, stream>>>(bptr, entries, row_ptr);

    // ---- x -> planes in d_out (d_out is free until the last layer) ----
    split_kernel<<<(N_NODES + 255) / 256, 256, 0, stream>>>(x, out);

    // ---- 4 layers x 2 half-passes; buf <-> d_out ping-pong in plane layout.
    // During one dispatch the chip gathers from a single 3.2-MB plane, which
    // is the only L2-allocating data (entries/row_ptr/out are NT).
    const int pgrid = (N_NODES * 2 + 255) / 256;   // 782 blocks
    // L1: d_out planes -> buf planes
    pull_half_kernel<<<pgrid, 256, 0, stream>>>(out, entries, row_ptr, buf, 0, 0);
    pull_half_kernel<<<pgrid, 256, 0, stream>>>(out, entries, row_ptr, buf, 1, 0);
    // L2: buf planes -> d_out planes
    pull_half_kernel<<<pgrid, 256, 0, stream>>>(buf, entries, row_ptr, out, 0, 0);
    pull_half_kernel<<<pgrid, 256, 0, stream>>>(buf, entries, row_ptr, out, 1, 0);
    // L3: d_out planes -> buf planes
    pull_half_kernel<<<pgrid, 256, 0, stream>>>(out, entries, row_ptr, buf, 0, 0);
    pull_half_kernel<<<pgrid, 256, 0, stream>>>(out, entries, row_ptr, buf, 1, 0);
    // L4: buf planes -> d_out INTERLEAVED (final layout)
    pull_half_kernel<<<pgrid, 256, 0, stream>>>(buf, entries, row_ptr, out, 0, 1);
    pull_half_kernel<<<pgrid, 256, 0, stream>>>(buf, entries, row_ptr, out, 1, 1);
}

// Round 6
// 316.189 us; speedup vs baseline: 1.8087x; 1.8087x over previous
//
#include <hip/hip_runtime.h>

#define N_NODES 100000
#define N_EDGES 3200000
#define BATCH 16
#define BKT_SHIFT 6
#define BKT_NODES 64
#define K_BUCKETS 1563                 // ceil(100000/64)
#define NB 512                         // subchunks (E/NB = 6250 exact)
#define SUB (N_EDGES / NB)             // 6250
#define FT 512                         // fill threads per block
#define SCAN_T 256
#define SCAN_C 7                       // 256*7 = 1792 >= 1563
#define CAP 4096                       // nodesort LDS capacity (bucket avg 2047, sigma 45)

// ---- phase 1: per-subchunk LDS histogram of row-buckets ----
__global__ void hist_kernel(const int* __restrict__ row, int* __restrict__ blk_cnt) {
    __shared__ int lh[K_BUCKETS];
    int t = threadIdx.x, blk = blockIdx.x;
    for (int k = t; k < K_BUCKETS; k += 256) lh[k] = 0;
    __syncthreads();
    int base = blk * SUB;
    for (int e = base + t; e < base + SUB; e += 256)
        atomicAdd(&lh[row[e] >> BKT_SHIFT], 1);
    __syncthreads();
    for (int k = t; k < K_BUCKETS; k += 256)
        blk_cnt[k * NB + blk] = lh[k];
}

// ---- phase 2: per-bucket exclusive prefix over the NB subchunks; totals.
// One WAVE per bucket: 64 lanes x 8 elements, wave-scan via shfl_up.
__global__ void colscan_kernel(int* __restrict__ blk_cnt, int* __restrict__ totals) {
    int wid = (blockIdx.x * blockDim.x + threadIdx.x) >> 6;
    int lane = threadIdx.x & 63;
    if (wid >= K_BUCKETS) return;
    int* p = &blk_cnt[wid * NB + lane * 8];
    int4 a = ((int4*)p)[0];
    int4 b = ((int4*)p)[1];
    int lt = a.x + a.y + a.z + a.w + b.x + b.y + b.z + b.w;
    // wave-inclusive scan of per-lane totals
    int pref = lt;
    #pragma unroll
    for (int off = 1; off < 64; off <<= 1) {
        int v = __shfl_up(pref, off, 64);
        if (lane >= off) pref += v;
    }
    int run = pref - lt;                 // exclusive base for this lane
    int4 oa, ob;
    oa.x = run; run += a.x;
    oa.y = run; run += a.y;
    oa.z = run; run += a.z;
    oa.w = run; run += a.w;
    ob.x = run; run += b.x;
    ob.y = run; run += b.y;
    ob.z = run; run += b.z;
    ob.w = run; run += b.w;
    ((int4*)p)[0] = oa;
    ((int4*)p)[1] = ob;
    int tot = __shfl(pref, 63, 64);      // inclusive total of bucket
    if (lane == 0) totals[wid] = tot;
}

// ---- phase 3: exclusive scan of 1563 bucket totals -> bptr ----
__global__ void scan_kernel(const int* __restrict__ totals, int* __restrict__ bptr,
                            int* __restrict__ row_ptr) {
    __shared__ int s[SCAN_T];
    int t = threadIdx.x;
    int loc[SCAN_C];
    int sum = 0;
    for (int i = 0; i < SCAN_C; i++) {
        int idx = t * SCAN_C + i;
        int v = (idx < K_BUCKETS) ? totals[idx] : 0;
        loc[i] = v;
        sum += v;
    }
    s[t] = sum;
    __syncthreads();
    for (int off = 1; off < SCAN_T; off <<= 1) {   // Hillis-Steele inclusive
        int x = (t >= off) ? s[t - off] : 0;
        __syncthreads();
        s[t] += x;
        __syncthreads();
    }
    int excl = s[t] - sum;
    for (int i = 0; i < SCAN_C; i++) {
        int idx = t * SCAN_C + i;
        if (idx < K_BUCKETS) bptr[idx] = excl;
        excl += loc[i];
    }
    if (t == 0) { bptr[K_BUCKETS] = N_EDGES; row_ptr[N_NODES] = N_EDGES; }
}

// ---- phase 4: LDS counting sort per 6250-edge subchunk, then run copy-out.
// 63.0 KB LDS -> 2 blocks/CU. record: x = (r_local<<17)|col, y = w bits.
__global__ void __launch_bounds__(FT) fill_kernel(
        const int* __restrict__ row, const int* __restrict__ col,
        const float* __restrict__ w,
        const int* __restrict__ bptr, const int* __restrict__ blk_cnt,
        uint2* __restrict__ entries) {
    __shared__ uint2 sbuf[SUB];          // 50000 B
    __shared__ int lbeg[K_BUCKETS];      // 6252 B
    __shared__ int lcur[K_BUCKETS];      // 6252 B
    __shared__ int sscan[FT];            // 2048 B   (total 63.0 KB)
    int t = threadIdx.x, blk = blockIdx.x;
    for (int k = t; k < K_BUCKETS; k += FT) lcur[k] = 0;
    __syncthreads();
    int base = blk * SUB;
    // pass 1: histogram into lcur
    for (int e = base + t; e < base + SUB; e += FT)
        atomicAdd(&lcur[row[e] >> BKT_SHIFT], 1);
    __syncthreads();
    // block-wide exclusive scan (each thread owns 4 buckets)
    int loc[4];
    int sum = 0;
    #pragma unroll
    for (int j = 0; j < 4; j++) {
        int k = t * 4 + j;
        int v = (k < K_BUCKETS) ? lcur[k] : 0;
        loc[j] = v;
        sum += v;
    }
    sscan[t] = sum;
    __syncthreads();
    for (int off = 1; off < FT; off <<= 1) {
        int x = (t >= off) ? sscan[t - off] : 0;
        __syncthreads();
        sscan[t] += x;
        __syncthreads();
    }
    int excl = sscan[t] - sum;
    #pragma unroll
    for (int j = 0; j < 4; j++) {
        int k = t * 4 + j;
        if (k < K_BUCKETS) { lbeg[k] = excl; lcur[k] = excl; }
        excl += loc[j];
    }
    __syncthreads();
    // pass 2: place records into LDS (bucket-sorted)
    for (int e = base + t; e < base + SUB; e += FT) {
        int r = row[e];
        int bkt = r >> BKT_SHIFT;
        int pos = atomicAdd(&lcur[bkt], 1);
        sbuf[pos] = make_uint2(((unsigned)(r & (BKT_NODES - 1)) << 17) | (unsigned)col[e],
                               __float_as_uint(w[e]));
    }
    __syncthreads();
    // pass 3: 4-lane subgroups copy each bucket run out (avg run ~4)
    int lane = t & 3;
    for (int k = (t >> 2); k < K_BUCKETS; k += FT / 4) {
        int lb = lbeg[k];
        int le = lcur[k];
        int dst = bptr[k] + blk_cnt[k * NB + blk];
        for (int i = lb + lane; i < le; i += 4)
            entries[dst + (i - lb)] = sbuf[i];
    }
}

// ---- phase 5 (+ layer 1 fused): per-bucket node sort (LDS-staged, register
// double-buffered), emits row_ptr and sorted entries, then immediately
// computes layer-1 output for the bucket's 64 nodes from the LDS-resident
// sorted edges (x gathers only; no entries/row_ptr re-read for layer 1).
// 33.5 KB LDS -> 4 blocks/CU = 16 waves for gather latency hiding.
__global__ void __launch_bounds__(256) nodesort_pull1_kernel(
        const int* __restrict__ bptr, uint2* __restrict__ entries,
        int* __restrict__ row_ptr,
        const float* __restrict__ x, float* __restrict__ out) {
    __shared__ uint2 ebuf[CAP];          // 32 KB
    __shared__ int nh[BKT_NODES];
    __shared__ int nc[BKT_NODES];
    __shared__ int nstart[BKT_NODES + 1];
    int t = threadIdx.x, b = blockIdx.x;
    int beg = bptr[b], end = bptr[b + 1];
    int n = min(end - beg, CAP);
    if (t < BKT_NODES) nh[t] = 0;
    __syncthreads();
    // phase A: load records to registers + LDS histogram
    uint2 rs[16];                        // 4096 / 256 = 16 max per thread
    int cnt = 0;
    #pragma unroll
    for (int i = 0; i < 16; i++) {
        int k = t + i * 256;
        if (k < n) {
            uint2 r = entries[beg + k];
            rs[i] = r;
            atomicAdd(&nh[r.x >> 17], 1);
            cnt = i + 1;
        }
    }
    __syncthreads();
    // phase B0: wave 0 shuffle-scans the 64 node counts; emits row_ptr
    if (t < BKT_NODES) {
        int v = nh[t];
        int pref = v;
        #pragma unroll
        for (int off = 1; off < BKT_NODES; off <<= 1) {
            int u = __shfl_up(pref, off, 64);
            if (t >= off) pref += u;
        }
        int excl = pref - v;
        nstart[t] = excl;
        nc[t] = excl;
        if (t == BKT_NODES - 1) nstart[BKT_NODES] = pref;
        int node = b * BKT_NODES + t;
        if (node < N_NODES) row_ptr[node] = beg + excl;
    }
    __syncthreads();
    // phase B1: scatter sorted into LDS ebuf AND global entries
    #pragma unroll
    for (int i = 0; i < 16; i++) {
        if (i < cnt) {
            uint2 r = rs[i];
            int pos = atomicAdd(&nc[r.x >> 17], 1);
            ebuf[pos] = r;
            entries[beg + pos] = r;
        }
    }
    __syncthreads();
    // phase C: layer-1 pull for this bucket (4 threads/node, float4 quads),
    // edges from LDS, y-gathers from x. Same serial segment walk as
    // pull_kernel -> identical accumulation order per (node, q).
    int ln = t >> 2, q = t & 3;
    int node = b * BKT_NODES + ln;
    if (node >= N_NODES) return;
    int s = nstart[ln], e = nstart[ln + 1];
    float4 acc = make_float4(0.f, 0.f, 0.f, 0.f);
    int i = s;
    while (i + 8 <= e) {
        uint2 r0 = ebuf[i + 0], r1 = ebuf[i + 1], r2 = ebuf[i + 2], r3 = ebuf[i + 3];
        uint2 r4 = ebuf[i + 4], r5 = ebuf[i + 5], r6 = ebuf[i + 6], r7 = ebuf[i + 7];
        float4 y0 = *(const float4*)&x[(r0.x & 0x1FFFFu) * BATCH + q * 4];
        float4 y1 = *(const float4*)&x[(r1.x & 0x1FFFFu) * BATCH + q * 4];
        float4 y2 = *(const float4*)&x[(r2.x & 0x1FFFFu) * BATCH + q * 4];
        float4 y3 = *(const float4*)&x[(r3.x & 0x1FFFFu) * BATCH + q * 4];
        float4 y4 = *(const float4*)&x[(r4.x & 0x1FFFFu) * BATCH + q * 4];
        float4 y5 = *(const float4*)&x[(r5.x & 0x1FFFFu) * BATCH + q * 4];
        float4 y6 = *(const float4*)&x[(r6.x & 0x1FFFFu) * BATCH + q * 4];
        float4 y7 = *(const float4*)&x[(r7.x & 0x1FFFFu) * BATCH + q * 4];
        float w0 = __uint_as_float(r0.y), w1 = __uint_as_float(r1.y);
        float w2 = __uint_as_float(r2.y), w3 = __uint_as_float(r3.y);
        float w4 = __uint_as_float(r4.y), w5 = __uint_as_float(r5.y);
        float w6 = __uint_as_float(r6.y), w7 = __uint_as_float(r7.y);
        acc.x += w0 * y0.x; acc.y += w0 * y0.y; acc.z += w0 * y0.z; acc.w += w0 * y0.w;
        acc.x += w1 * y1.x; acc.y += w1 * y1.y; acc.z += w1 * y1.z; acc.w += w1 * y1.w;
        acc.x += w2 * y2.x; acc.y += w2 * y2.y; acc.z += w2 * y2.z; acc.w += w2 * y2.w;
        acc.x += w3 * y3.x; acc.y += w3 * y3.y; acc.z += w3 * y3.z; acc.w += w3 * y3.w;
        acc.x += w4 * y4.x; acc.y += w4 * y4.y; acc.z += w4 * y4.z; acc.w += w4 * y4.w;
        acc.x += w5 * y5.x; acc.y += w5 * y5.y; acc.z += w5 * y5.z; acc.w += w5 * y5.w;
        acc.x += w6 * y6.x; acc.y += w6 * y6.y; acc.z += w6 * y6.z; acc.w += w6 * y6.w;
        acc.x += w7 * y7.x; acc.y += w7 * y7.y; acc.z += w7 * y7.z; acc.w += w7 * y7.w;
        i += 8;
    }
    for (; i < e; i++) {
        uint2 r = ebuf[i];
        float4 yv = *(const float4*)&x[(r.x & 0x1FFFFu) * BATCH + q * 4];
        float wj = __uint_as_float(r.y);
        acc.x += wj * yv.x; acc.y += wj * yv.y;
        acc.z += wj * yv.z; acc.w += wj * yv.w;
    }
    *(float4*)&out[node * BATCH + q * 4] = acc;
}

// ---- layers 2-4: node-parallel CSR pull, float4 batch quads (4 threads/node).
// Plain cached loads/stores (NT proven net-negative on gfx950 in R3/R5).
__global__ void __launch_bounds__(256) pull_kernel(const float* __restrict__ y,
                            const uint2* __restrict__ entries,
                            const int* __restrict__ row_ptr,
                            float* __restrict__ out) {
    int tid = blockIdx.x * blockDim.x + threadIdx.x;
    int node = tid >> 2;
    int q = tid & 3;
    if (node >= N_NODES) return;
    int beg = row_ptr[node];
    int end = row_ptr[node + 1];
    float4 acc = make_float4(0.f, 0.f, 0.f, 0.f);
    if (beg < end) {
        int lim = end - 1;
        uint2 r[8];
        #pragma unroll
        for (int j = 0; j < 8; j++) r[j] = entries[min(beg + j, lim)];
        int i = beg;
        while (i + 8 <= end) {
            float4 yv[8];
            #pragma unroll
            for (int j = 0; j < 8; j++)
                yv[j] = *(const float4*)&y[(r[j].x & 0x1FFFFu) * BATCH + q * 4];
            uint2 nx[8];
            #pragma unroll
            for (int j = 0; j < 8; j++)
                nx[j] = entries[min(i + 8 + j, lim)];
            #pragma unroll
            for (int j = 0; j < 8; j++) {
                float wj = __uint_as_float(r[j].y);
                acc.x += wj * yv[j].x;
                acc.y += wj * yv[j].y;
                acc.z += wj * yv[j].z;
                acc.w += wj * yv[j].w;
            }
            #pragma unroll
            for (int j = 0; j < 8; j++) r[j] = nx[j];
            i += 8;
        }
        if (i < end) {                       // masked epilogue, still batched
            float4 yv[8];
            #pragma unroll
            for (int j = 0; j < 8; j++)
                yv[j] = *(const float4*)&y[(r[j].x & 0x1FFFFu) * BATCH + q * 4];
            #pragma unroll
            for (int j = 0; j < 8; j++)
                if (i + j < end) {
                    float wj = __uint_as_float(r[j].y);
                    acc.x += wj * yv[j].x;
                    acc.y += wj * yv[j].y;
                    acc.z += wj * yv[j].z;
                    acc.w += wj * yv[j].w;
                }
        }
    }
    *(float4*)&out[node * BATCH + q * 4] = acc;
}

extern "C" void kernel_launch(void* const* d_in, const int* in_sizes, int n_in,
                              void* d_out, int out_size, void* d_ws, size_t ws_size,
                              hipStream_t stream) {
    const float* x   = (const float*)d_in[0];
    const float* w   = (const float*)d_in[1];
    const int*   row = (const int*)d_in[2];
    const int*   col = (const int*)d_in[3];
    float*       out = (float*)d_out;

    // ---- workspace carve-up (~32.4 MB; proven ws >= 33.2 MB) ----
    char* p = (char*)d_ws;
    uint2* entries = (uint2*)p;  p += (size_t)N_EDGES * sizeof(uint2);           // 25.6 MB
    float* buf     = (float*)p;                                                   // 6.4 MB
    int*   blk_cnt = (int*)buf;  // 3.2 MB alias: dead before nodesort_pull1 writes buf
    p += (size_t)N_NODES * BATCH * sizeof(float);
    int* totals  = (int*)p;      p += 8192;
    int* bptr    = (int*)p;      p += 8192;
    int* row_ptr = (int*)p;      // 400 KB

    // ---- build exact per-node CSR (once; reused by all 4 layers) ----
    hist_kernel<<<NB, 256, 0, stream>>>(row, blk_cnt);
    colscan_kernel<<<(K_BUCKETS * 64 + 255) / 256, 256, 0, stream>>>(blk_cnt, totals);
    scan_kernel<<<1, SCAN_T, 0, stream>>>(totals, bptr, row_ptr);
    fill_kernel<<<NB, FT, 0, stream>>>(row, col, w, bptr, blk_cnt, entries);

    // ---- nodesort + layer 1 fused (x -> buf), then layers 2-4 ----
    nodesort_pull1_kernel<<<K_BUCKETS, 256, 0, stream>>>(bptr, entries, row_ptr, x, buf);
    const int pgrid = (N_NODES * 4 + 255) / 256;   // 1563 blocks, 4 threads/node
    pull_kernel<<<pgrid, 256, 0, stream>>>(buf, entries, row_ptr, out);  // buf -> out
    pull_kernel<<<pgrid, 256, 0, stream>>>(out, entries, row_ptr, buf);  // out -> buf
    pull_kernel<<<pgrid, 256, 0, stream>>>(buf, entries, row_ptr, out);  // buf -> out
}